// Round 15
// baseline (1091.972 us; speedup 1.0000x reference)
//
#include <hip/hip_runtime.h>

typedef __bf16 bf16;
typedef float f32x4 __attribute__((ext_vector_type(4)));
typedef __bf16 b8v __attribute__((ext_vector_type(8)));
typedef __bf16 b4v __attribute__((ext_vector_type(4)));

#define S_LEN 2048
#define DMODEL 512
#define KDIM 128
#define NWIN 16
#define WIN 128
#define QKVS 1536   // fused qkv row stride

__device__ inline f32x4 mfma16(b8v a, b8v b, f32x4 c) {
  return __builtin_amdgcn_mfma_f32_16x16x32_bf16(a, b, c, 0, 0, 0);
}

__device__ inline void gload16(const bf16* g, bf16* l) {
  __builtin_amdgcn_global_load_lds(
      (const __attribute__((address_space(1))) void*)g,
      (__attribute__((address_space(3))) void*)l, 16, 0, 0);
}

template<int N>
__device__ inline void waitvm() { asm volatile("s_waitcnt vmcnt(%0)" :: "n"(N) : "memory"); }
template<int N>
__device__ inline void waitlgkm() { asm volatile("s_waitcnt lgkmcnt(%0)" :: "n"(N) : "memory"); }
__device__ inline void barrier_raw() { asm volatile("s_barrier" ::: "memory"); }

// ---------------- conversion kernels ----------------

__global__ __launch_bounds__(256) void conv_kernel(const float* __restrict__ in, bf16* __restrict__ out, int n) {
  int i4 = (blockIdx.x * 256 + threadIdx.x) * 4;
  if (i4 < n) {
    float4 v = *(const float4*)(in + i4);
    b4v o; o[0] = (bf16)v.x; o[1] = (bf16)v.y; o[2] = (bf16)v.z; o[3] = (bf16)v.w;
    *(b4v*)(out + i4) = o;
  }
}

// generic W (Kd x N) f32 -> WT (N x Kd) bf16
__global__ __launch_bounds__(256) void convT_kernel(const float* __restrict__ W, bf16* __restrict__ WT,
                                                    int Kd, int N, size_t in_ls, size_t out_ls) {
  __shared__ float tile[32][33];
  int k0 = blockIdx.x * 32, n0 = blockIdx.y * 32;
  const float* Wl = W + (size_t)blockIdx.z * in_ls;
  bf16* WTl = WT + (size_t)blockIdx.z * out_ls;
  int tx = threadIdx.x & 31, ty = threadIdx.x >> 5;
  #pragma unroll
  for (int i = 0; i < 4; i++)
    tile[ty + i*8][tx] = Wl[(size_t)(k0 + ty + i*8) * N + n0 + tx];
  __syncthreads();
  #pragma unroll
  for (int i = 0; i < 4; i++)
    WTl[(size_t)(n0 + ty + i*8) * Kd + k0 + tx] = (bf16)tile[tx][ty + i*8];
}

// fused transpose for wq/wk/wv/wo (all [4][512][512]); z = layer*4 + which
__global__ __launch_bounds__(256) void convT4_kernel(
    const float* __restrict__ wq, const float* __restrict__ wk,
    const float* __restrict__ wv, const float* __restrict__ wo,
    bf16* __restrict__ wqkvT, bf16* __restrict__ woT) {
  __shared__ float tile[32][33];
  int z = blockIdx.z, layer = z >> 2, which = z & 3;
  const float* W = (which == 0 ? wq : which == 1 ? wk : which == 2 ? wv : wo)
                   + (size_t)layer * 262144;
  bf16* WT = (which < 3) ? (wqkvT + (size_t)layer * 786432 + (size_t)which * 262144)
                         : (woT + (size_t)layer * 262144);
  int k0 = blockIdx.x * 32, n0 = blockIdx.y * 32;
  int tx = threadIdx.x & 31, ty = threadIdx.x >> 5;
  #pragma unroll
  for (int i = 0; i < 4; i++)
    tile[ty + i*8][tx] = W[(size_t)(k0 + ty + i*8) * 512 + n0 + tx];
  __syncthreads();
  #pragma unroll
  for (int i = 0; i < 4; i++)
    WT[(size_t)(n0 + ty + i*8) * 512 + k0 + tx] = (bf16)tile[tx][ty + i*8];
}

// ---------------- time embedding MLP ----------------

__global__ __launch_bounds__(256) void time1_kernel(const int* __restrict__ t,
    const float* __restrict__ w1, const float* __restrict__ b1, float* __restrict__ te1) {
  __shared__ float te[512];
  __shared__ float red[4][64];
  int b = blockIdx.x >> 5;
  int c0 = (blockIdx.x & 31) * 64;
  int tid = threadIdx.x;
  float tt = (float)t[b] * 4.0f;
  {
    float fr = expf((float)tid * (-9.210340371976184f / 255.0f));
    float e = tt * fr;
    te[tid] = sinf(e);
    te[tid + 256] = cosf(e);
  }
  __syncthreads();
  int lane = tid & 63, wv = tid >> 6;
  float acc = 0.f;
  const float* wcol = w1 + (size_t)(wv * 128) * 2048 + c0 + lane;
  for (int dd = 0; dd < 128; dd++) acc = fmaf(te[wv * 128 + dd], wcol[(size_t)dd * 2048], acc);
  red[wv][lane] = acc;
  __syncthreads();
  if (tid < 64) {
    float a = red[0][tid] + red[1][tid] + red[2][tid] + red[3][tid] + b1[c0 + tid];
    float sp = (a > 20.f) ? a : log1pf(expf(a));
    te1[b * 2048 + c0 + tid] = a * tanhf(sp);
  }
}

__global__ __launch_bounds__(256) void time2_kernel(const float* __restrict__ te1,
    const float* __restrict__ w2, const float* __restrict__ b2, float* __restrict__ te2) {
  __shared__ float hb[2048];
  __shared__ float red[4][64];
  int b = blockIdx.x >> 3;
  int c0 = (blockIdx.x & 7) * 64;
  int tid = threadIdx.x;
  for (int i = tid; i < 2048; i += 256) hb[i] = te1[b * 2048 + i];
  __syncthreads();
  int lane = tid & 63, wv = tid >> 6;
  float acc = 0.f;
  const float* wcol = w2 + (size_t)(wv * 512) * 512 + c0 + lane;
  for (int dd = 0; dd < 512; dd++) acc = fmaf(hb[wv * 512 + dd], wcol[(size_t)dd * 512], acc);
  red[wv][lane] = acc;
  __syncthreads();
  if (tid < 64)
    te2[b * 512 + c0 + tid] = red[0][tid] + red[1][tid] + red[2][tid] + red[3][tid] + b2[c0 + tid];
}

// ---------------- layernorm: bf16 in -> bf16 out ----------------

__global__ __launch_bounds__(256) void ln_kernel(const bf16* __restrict__ hsrc,
    const float* __restrict__ gg, const float* __restrict__ bb, bf16* __restrict__ out) {
  int row = blockIdx.x * 4 + (threadIdx.x >> 6);
  int lane = threadIdx.x & 63;
  const bf16* hr = hsrc + (size_t)row * 512 + lane * 8;
  b8v hv = *(const b8v*)hr;
  float xv[8];
  #pragma unroll
  for (int j = 0; j < 8; j++) xv[j] = (float)hv[j];
  float s = 0.f;
  #pragma unroll
  for (int j = 0; j < 8; j++) s += xv[j];
  #pragma unroll
  for (int off = 1; off < 64; off <<= 1) s += __shfl_xor(s, off);
  float mu = s * (1.f / 512.f);
  float vs = 0.f;
  #pragma unroll
  for (int j = 0; j < 8; j++) { float dd = xv[j] - mu; vs += dd * dd; }
  #pragma unroll
  for (int off = 1; off < 64; off <<= 1) vs += __shfl_xor(vs, off);
  float rstd = 1.f / sqrtf(vs * (1.f / 512.f) + 1e-5f);
  int dbase = lane * 8;
  bf16* orow = out + (size_t)row * 512 + dbase;
  #pragma unroll
  for (int j = 0; j < 8; j++)
    orow[j] = (bf16)((xv[j] - mu) * rstd * gg[dbase + j] + bb[dbase + j]);
}

// ---------------- phased MFMA GEMM (multi-block/CU, coalesced LDS epilogue) ----
// C(MxN) = A(MxK,bf16) * BT(NxK,bf16)^T ; 512 threads, 8 waves (2M x 4N); BK=32.
// 3 LDS k-tile buffers, 2-tiles-ahead prefetch; ONE vmcnt(LPI) + ONE s_barrier per
// K-tile. BM=128,BN=256 -> 72KB -> 2 blocks/CU; BM=128,BN=128 -> 48KB -> 3/CU.
// Epilogue: scatter bf16 results into padded LDS tile [128][BN+8], then stream
// 16B-coalesced chunks (EPI2 does vector RMW; EPI5 adds pos/time embeddings).
// EPI 0: Cb = acc ; 2: Cb += acc+bias ; 3: Cb = gelu_tanh(acc+bias)
// EPI 5: Cb = acc+bias + ax1 + ax2 + te2 (token embed + pos)
template<int EPI, int BM, int BN>
__global__ __launch_bounds__(512, 2) void gemm3_kernel(
    const bf16* __restrict__ A, const bf16* __restrict__ BT,
    const float* __restrict__ bias, bf16* __restrict__ Cb,
    int N, int Kd, int nbx,
    const float* __restrict__ q1, const float* __restrict__ q2, const float* __restrict__ q3) {
  constexpr int LA = BM / 128;
  constexpr int LB = BN / 128;
  constexpr int LPI = LA + LB;
  constexpr int EA = BM * 32;
  constexpr int EB = BN * 32;
  constexpr int ER = EA + EB;
  constexpr int MF = BM / 32;
  constexpr int NF = BN / 64;
  __shared__ bf16 lds[ER * 3];
  int tid = threadIdx.x;
  int lane = tid & 63, wid = tid >> 6;
  int g = lane >> 4, lr = lane & 15;
  int wm = wid >> 2, wn = wid & 3;
  int p = blockIdx.x;
  int cpx = (int)gridDim.x >> 3;
  int vid = (p & 7) * cpx + (p >> 3);
  int m0 = (vid / nbx) * BM;
  int n0 = (vid % nbx) * BN;
  f32x4 acc[MF][NF] = {};
  int rl = tid >> 2;
  int csw = ((tid & 3) ^ ((rl >> 1) & 3)) * 8;
  const bf16* pa = A + (size_t)(m0 + rl) * Kd + csw;
  const bf16* pb = BT + (size_t)(n0 + rl) * Kd + csw;
  int NT = Kd >> 5;
  auto stage = [&](int t, int buf) {
    int k0 = t << 5;
    bf16* base = lds + buf * ER + (wid << 9);
    #pragma unroll
    for (int rr = 0; rr < LA; rr++)
      gload16(pa + (size_t)(rr * 128) * Kd + k0, base + rr * 4096);
    #pragma unroll
    for (int rr = 0; rr < LB; rr++)
      gload16(pb + (size_t)(rr * 128) * Kd + k0, base + EA + rr * 4096);
  };
  stage(0, 0);
  stage(1, 1);
  for (int kt = 0; kt < NT; ++kt) {
    if (kt + 1 < NT) waitvm<LPI>();
    else             waitvm<0>();
    barrier_raw();
    const bf16* ba = lds + (kt % 3) * ER;
    const bf16* bb = ba + EA;
    if (kt + 2 < NT) stage(kt + 2, (kt + 2) % 3);
    b8v af[MF], bfr[NF];
    #pragma unroll
    for (int i = 0; i < MF; i++) {
      int ra = wm * (BM / 2) + i * 16 + lr;
      af[i] = *(const b8v*)(ba + ra * 32 + ((g * 8) ^ (((ra >> 1) & 3) << 3)));
    }
    #pragma unroll
    for (int j0 = 0; j0 < 2 && j0 < NF; j0++) {
      int rb = wn * (BN / 4) + j0 * 16 + lr;
      bfr[j0] = *(const b8v*)(bb + rb * 32 + ((g * 8) ^ (((rb >> 1) & 3) << 3)));
    }
    waitlgkm<0>();
    __builtin_amdgcn_sched_barrier(0);
    __builtin_amdgcn_s_setprio(1);
    #pragma unroll
    for (int i = 0; i < MF; i++) acc[i][0] = mfma16(af[i], bfr[0], acc[i][0]);
    __builtin_amdgcn_s_setprio(0);
    #pragma unroll
    for (int j = 1; j < NF; j++) {
      if (j + 1 < NF) {
        int rb = wn * (BN / 4) + (j + 1) * 16 + lr;
        bfr[j + 1] = *(const b8v*)(bb + rb * 32 + ((g * 8) ^ (((rb >> 1) & 3) << 3)));
        waitlgkm<1>();
      } else {
        waitlgkm<0>();
      }
      __builtin_amdgcn_sched_barrier(0);
      __builtin_amdgcn_s_setprio(1);
      #pragma unroll
      for (int i = 0; i < MF; i++) acc[i][j] = mfma16(af[i], bfr[j], acc[i][j]);
      __builtin_amdgcn_s_setprio(0);
    }
  }
  // ---- coalesced epilogue via LDS (staging buffers are dead after barrier) ----
  constexpr int PD = BN + 8;               // padded row stride (breaks bank alias)
  bf16* ct = lds;                          // BM*PD elems <= ER*3 (checked both geoms)
  barrier_raw();
  #pragma unroll
  for (int i = 0; i < MF; i++) {
    #pragma unroll
    for (int j = 0; j < NF; j++) {
      int col = wn * (BN / 4) + j * 16 + lr;
      float bv = (EPI != 0) ? bias[n0 + col] : 0.0f;
      #pragma unroll
      for (int r = 0; r < 4; r++) {
        int row = wm * (BM / 2) + i * 16 + g * 4 + r;
        float v = acc[i][j][r] + bv;
        if (EPI == 3) {
          float u = 1.5957691216057308f * (v + 0.044715f * v * v * v);
          v = v / (1.0f + __expf(-u));
        }
        ct[row * PD + col] = (bf16)v;
      }
    }
  }
  barrier_raw();
  constexpr int CH = BN / 32;              // 16B chunks per thread
  int row_l = tid >> 2, colb = (tid & 3) * (BN / 4);
  int grow = m0 + row_l;
  #pragma unroll
  for (int c = 0; c < CH; c++) {
    int col = colb + c * 8;
    b8v v = *(const b8v*)(ct + row_l * PD + col);
    size_t gidx = (size_t)grow * N + n0 + col;
    if (EPI == 2) {
      b8v o = *(const b8v*)(Cb + gidx);
      #pragma unroll
      for (int e = 0; e < 8; e++) v[e] = (bf16)((float)o[e] + (float)v[e]);
    } else if (EPI == 5) {
      int b_ = grow >> 11, s_ = grow & 2047;
      #pragma unroll
      for (int e = 0; e < 8; e++) {
        int cc = n0 + col + e;
        v[e] = (bf16)((float)v[e] + q1[(s_ >> 7) * 512 + cc] + q2[(s_ & 127) * 512 + cc] + q3[b_ * 512 + cc]);
      }
    }
    *(b8v*)(Cb + gidx) = v;
  }
}

// ---------------- small-GEMM kernel (output EPI4 transpose) ----
__global__ __launch_bounds__(256) void gemm_kernel(
    const bf16* __restrict__ A, const bf16* __restrict__ BT,
    const float* __restrict__ bias, float* __restrict__ Cf,
    int N, int Kd, int nbx, const float* __restrict__ alphap) {
  __shared__ bf16 As[2][4096];
  __shared__ bf16 Bs[2][4096];
  int tid = threadIdx.x;
  int lane = tid & 63, wid = tid >> 6;
  int g = lane >> 4, lr = lane & 15;
  int wm = wid >> 1, wn = wid & 1;
  int p = blockIdx.x;
  int cpx = (int)gridDim.x >> 3;
  int vid = (p & 7) * cpx + (p >> 3);
  int m0 = (vid / nbx) * 128;
  int n0 = (vid % nbx) * 128;
  f32x4 acc[4][4] = {};
  int srow = wid * 16 + (lane >> 2);
  int scol = (lane & 3) * 8;
  const bf16* pa = A + (size_t)(m0 + srow) * Kd + scol;
  const bf16* pb = BT + (size_t)(n0 + srow) * Kd + scol;
  const size_t rstep = (size_t)64 * Kd;
  int nt = Kd >> 5;
  auto stage = [&](int buf, int k0) {
    bf16* lA = &As[buf][wid * 512];
    bf16* lB = &Bs[buf][wid * 512];
    gload16(pa + k0, lA);
    gload16(pa + rstep + k0, lA + 2048);
    gload16(pb + k0, lB);
    gload16(pb + rstep + k0, lB + 2048);
  };
  stage(0, 0);
  __syncthreads();
  int cur = 0;
  for (int t = 0; t < nt; ++t) {
    if (t + 1 < nt) stage(cur ^ 1, (t + 1) * 32);
    b8v af[4], bfv[4];
    #pragma unroll
    for (int i = 0; i < 4; i++) af[i]  = *(const b8v*)&As[cur][(wm * 64 + i * 16 + lr) * 32 + g * 8];
    #pragma unroll
    for (int i = 0; i < 4; i++) bfv[i] = *(const b8v*)&Bs[cur][(wn * 64 + i * 16 + lr) * 32 + g * 8];
    #pragma unroll
    for (int mf = 0; mf < 4; mf++)
      #pragma unroll
      for (int nf = 0; nf < 4; nf++)
        acc[mf][nf] = mfma16(af[mf], bfv[nf], acc[mf][nf]);
    __syncthreads();
    cur ^= 1;
  }
  __shared__ float Ts[32][130];
  float alp = alphap[0];
  int b_ = m0 >> 11, sb = m0 & 2047;
  #pragma unroll
  for (int cg = 0; cg < 4; cg++) {
    __syncthreads();
    if (wn == (cg >> 1)) {
      #pragma unroll
      for (int nfi = 0; nfi < 2; nfi++) {
        int nf = (cg & 1) * 2 + nfi;
        int cl = nfi * 16 + lr;
        float bv = bias[cg * 32 + cl];
        #pragma unroll
        for (int mf = 0; mf < 4; mf++)
          #pragma unroll
          for (int r = 0; r < 4; r++)
            Ts[cl][wm * 64 + mf * 16 + g * 4 + r] = alp * (acc[mf][nf][r] + bv);
      }
    }
    __syncthreads();
    int cl = tid >> 3, soff = (tid & 7) * 16;
    int col = cg * 32 + cl;
    float* dst = Cf + (size_t)b_ * (KDIM * S_LEN) + (size_t)col * S_LEN + sb + soff;
    #pragma unroll
    for (int q4 = 0; q4 < 4; q4++) {
      float4 v = {Ts[cl][soff + q4*4], Ts[cl][soff + q4*4 + 1], Ts[cl][soff + q4*4 + 2], Ts[cl][soff + q4*4 + 3]};
      *(float4*)(dst + q4 * 4) = v;
    }
  }
}

// ---------------- merged attention part 1: local attn (y<32) + la2 (y>=32) ----
__global__ __launch_bounds__(256) void attn_kernel(
    const bf16* __restrict__ qkv, bf16* __restrict__ ab,
    float* __restrict__ part, float* __restrict__ psum) {
  __shared__ __align__(16) char smem[70656];
  int tid = threadIdx.x;
  if (blockIdx.y < 32) {
    bf16 (*Ks)[72]  = (bf16(*)[72])(smem);
    bf16 (*Vt)[136] = (bf16(*)[136])(smem + 18432);
    bf16 (*Ps)[32][136] = (bf16(*)[32][136])(smem + 35840);
    int w = blockIdx.x;
    int b = blockIdx.y >> 2, hh = blockIdx.y & 3;
    int wid = tid >> 6, lane = tid & 63;
    int g = lane >> 4, lr = lane & 15;
    const size_t rowb = (size_t)b * S_LEN * QKVS;
    int qrow0 = w * WIN + wid * 32;
    b8v qf[2][2];
    #pragma unroll
    for (int mf = 0; mf < 2; mf++)
      #pragma unroll
      for (int kf = 0; kf < 2; kf++)
        qf[mf][kf] = *(const b8v*)(qkv + rowb + (size_t)(qrow0 + mf * 16 + lr) * QKVS + hh * 64 + kf * 32 + g * 8);
    float mrun[2][4], lrun[2][4];
    f32x4 oacc[2][4] = {};
    #pragma unroll
    for (int mf = 0; mf < 2; mf++)
      #pragma unroll
      for (int r = 0; r < 4; r++) { mrun[mf][r] = -3e38f; lrun[mf][r] = 0.f; }
    for (int c = 0; c < 3; c++) {
      int wc = w - 1 + c;
      if (wc < 0 || wc >= NWIN) continue;
      __syncthreads();
      {
        int row = tid >> 1, f0 = (tid & 1) * 32;
        const bf16* kp = qkv + rowb + (size_t)(wc * WIN + row) * QKVS + 512 + hh * 64 + f0;
        #pragma unroll
        for (int i = 0; i < 4; i++)
          *(b8v*)&Ks[row][f0 + i * 8] = *(const b8v*)(kp + i * 8);
        const bf16* vp = qkv + rowb + (size_t)(wc * WIN + row) * QKVS + 1024 + hh * 64 + f0;
        #pragma unroll
        for (int i = 0; i < 4; i++) {
          b8v vv = *(const b8v*)(vp + i * 8);
          #pragma unroll
          for (int j = 0; j < 8; j++) Vt[f0 + i * 8 + j][row] = vv[j];
        }
      }
      __syncthreads();
      f32x4 sc[2][8] = {};
      #pragma unroll
      for (int nf = 0; nf < 8; nf++) {
        #pragma unroll
        for (int kf = 0; kf < 2; kf++) {
          b8v kfr = *(const b8v*)&Ks[nf * 16 + lr][kf * 32 + g * 8];
          sc[0][nf] = mfma16(qf[0][kf], kfr, sc[0][nf]);
          sc[1][nf] = mfma16(qf[1][kf], kfr, sc[1][nf]);
        }
      }
      #pragma unroll
      for (int mf = 0; mf < 2; mf++) {
        #pragma unroll
        for (int r = 0; r < 4; r++) {
          float cm = -3e38f;
          #pragma unroll
          for (int nf = 0; nf < 8; nf++) { sc[mf][nf][r] *= 0.125f; cm = fmaxf(cm, sc[mf][nf][r]); }
          cm = fmaxf(cm, __shfl_xor(cm, 1));
          cm = fmaxf(cm, __shfl_xor(cm, 2));
          cm = fmaxf(cm, __shfl_xor(cm, 4));
          cm = fmaxf(cm, __shfl_xor(cm, 8));
          float mnew = fmaxf(mrun[mf][r], cm);
          float corr = __expf(mrun[mf][r] - mnew);
          float rs = 0.f;
          #pragma unroll
          for (int nf = 0; nf < 8; nf++) { float pv = __expf(sc[mf][nf][r] - mnew); sc[mf][nf][r] = pv; rs += pv; }
          rs += __shfl_xor(rs, 1); rs += __shfl_xor(rs, 2);
          rs += __shfl_xor(rs, 4); rs += __shfl_xor(rs, 8);
          lrun[mf][r] = lrun[mf][r] * corr + rs;
          mrun[mf][r] = mnew;
          #pragma unroll
          for (int vf = 0; vf < 4; vf++) oacc[mf][vf][r] *= corr;
        }
      }
      #pragma unroll
      for (int mf = 0; mf < 2; mf++)
        #pragma unroll
        for (int nf = 0; nf < 8; nf++)
          #pragma unroll
          for (int r = 0; r < 4; r++)
            Ps[wid][mf * 16 + g * 4 + r][nf * 16 + lr] = (bf16)sc[mf][nf][r];
      #pragma unroll
      for (int kf2 = 0; kf2 < 4; kf2++) {
        b8v pa0 = *(const b8v*)&Ps[wid][lr][kf2 * 32 + g * 8];
        b8v pa1 = *(const b8v*)&Ps[wid][16 + lr][kf2 * 32 + g * 8];
        #pragma unroll
        for (int vf = 0; vf < 4; vf++) {
          b8v vv = *(const b8v*)&Vt[vf * 16 + lr][kf2 * 32 + g * 8];
          oacc[0][vf] = mfma16(pa0, vv, oacc[0][vf]);
          oacc[1][vf] = mfma16(pa1, vv, oacc[1][vf]);
        }
      }
    }
    #pragma unroll
    for (int mf = 0; mf < 2; mf++) {
      #pragma unroll
      for (int r = 0; r < 4; r++) {
        float inv = 1.0f / lrun[mf][r];
        int row = qrow0 + mf * 16 + g * 4 + r;
        #pragma unroll
        for (int vf = 0; vf < 4; vf++)
          ab[(size_t)b * S_LEN * DMODEL + (size_t)row * DMODEL + hh * 64 + vf * 16 + lr] = (bf16)(oacc[mf][vf][r] * inv);
      }
    }
  } else {
    float (*ke)[65]  = (float(*)[65])(smem);
    float (*vsh)[65] = (float(*)[65])(smem + 33280);
    float (*red)[64] = (float(*)[64])(smem + 66560);
    int ch = blockIdx.x, bh = blockIdx.y - 32;
    int b = bh >> 2, hh = bh & 3;
    const float scale = 0.35355339059327373f;
    const size_t base = ((size_t)b * S_LEN + (size_t)ch * 128) * QKVS;
    const bf16* kp = qkv + base + 768 + hh * 64;
    const bf16* vp = qkv + base + 1280 + hh * 64;
    for (int i = tid; i < 1024; i += 256) {
      int s = i >> 3, d0 = (i & 7) * 8;
      b8v kv = *(const b8v*)(kp + (size_t)s * QKVS + d0);
      b8v vv = *(const b8v*)(vp + (size_t)s * QKVS + d0);
      #pragma unroll
      for (int j = 0; j < 8; j++) {
        ke[s][d0 + j] = __expf((float)kv[j] * scale);
        vsh[s][d0 + j] = (float)vv[j];
      }
    }
    __syncthreads();
    int d = tid & 63, sg = tid >> 6;
    float ps = 0.f;
    for (int s = sg * 32; s < sg * 32 + 32; s++) ps += ke[s][d];
    red[sg][d] = ps;
    int e = tid & 63, dg = tid >> 6;
    float accv[16] = {};
    for (int s = 0; s < 128; s++) {
      float vv2 = vsh[s][e];
      #pragma unroll
      for (int i = 0; i < 16; i++) accv[i] = fmaf(ke[s][dg * 16 + i], vv2, accv[i]);
    }
    __syncthreads();
    float* pp = part + ((size_t)ch * 32 + bh) * 4096 + (size_t)dg * 16 * 64 + e;
    #pragma unroll
    for (int i = 0; i < 16; i++) pp[i * 64] = accv[i];
    if (tid < 64)
      psum[((size_t)ch * 32 + bh) * 64 + tid] = red[0][tid] + red[1][tid] + red[2][tid] + red[3][tid];
  }
}

__global__ __launch_bounds__(256) void la2b_kernel(const float* __restrict__ part,
    const float* __restrict__ psum, float* __restrict__ ctx) {
  int idx = blockIdx.x * 256 + threadIdx.x;    // 131072 total
  int bh = idx >> 12;
  int d = (idx >> 6) & 63;
  float s = 0.f, cs = 0.f;
  for (int c = 0; c < 16; c++) {
    s += part[(size_t)c * 131072 + idx];
    cs += psum[(size_t)(c * 32 + bh) * 64 + d];
  }
  ctx[idx] = s / cs;
}

__global__ __launch_bounds__(256) void la3_kernel(const bf16* __restrict__ qkv,
    const float* __restrict__ ctx, bf16* __restrict__ ab) {
  int ch = blockIdx.x, bh = blockIdx.y;
  int b = bh >> 2, hh = bh & 3;
  __shared__ float cs[64][65];
  int tid = threadIdx.x;
  for (int i = tid; i < 4096; i += 256) cs[i >> 6][i & 63] = ctx[(size_t)bh * 4096 + i];
  __syncthreads();
  int s = ch * 128 + (tid >> 1);
  int e0 = (tid & 1) * 32;
  const float scale = 0.35355339059327373f;
  const bf16* qr = qkv + ((size_t)b * S_LEN + s) * QKVS + 256 + hh * 64;
  float qv[64];
  float mx = -3e38f;
  #pragma unroll
  for (int i = 0; i < 8; i++) {
    b8v qq = *(const b8v*)(qr + i * 8);
    #pragma unroll
    for (int j = 0; j < 8; j++) { qv[i * 8 + j] = (float)qq[j] * scale; mx = fmaxf(mx, qv[i * 8 + j]); }
  }
  float sum = 0.f;
  #pragma unroll
  for (int dd = 0; dd < 64; dd++) { qv[dd] = __expf(qv[dd] - mx); sum += qv[dd]; }
  float inv = 1.f / sum;
  float o[32] = {};
  #pragma unroll
  for (int dd = 0; dd < 64; dd++) {
    float qq = qv[dd] * inv;
    #pragma unroll
    for (int j = 0; j < 32; j++) o[j] = fmaf(qq, cs[dd][e0 + j], o[j]);
  }
  bf16* op = ab + ((size_t)b * S_LEN + s) * DMODEL + 256 + hh * 64 + e0;
  #pragma unroll
  for (int j = 0; j < 32; j++) op[j] = (bf16)o[j];
}

// ---------------- launcher ----------------

extern "C" void kernel_launch(void* const* d_in, const int* in_sizes, int n_in,
                              void* d_out, int out_size, void* d_ws, size_t ws_size,
                              hipStream_t stream) {
  (void)in_sizes; (void)n_in; (void)out_size; (void)ws_size;
  const float* x_f     = (const float*)d_in[0];
  const int*   t_i     = (const int*)  d_in[1];
  const float* token_w = (const float*)d_in[2];
  const float* token_b = (const float*)d_in[3];
  const float* ax1     = (const float*)d_in[4];
  const float* ax2     = (const float*)d_in[5];
  const float* time_w1 = (const float*)d_in[6];
  const float* time_b1 = (const float*)d_in[7];
  const float* time_w2 = (const float*)d_in[8];
  const float* time_b2 = (const float*)d_in[9];
  const float* ln1_g   = (const float*)d_in[10];
  const float* ln1_b   = (const float*)d_in[11];
  const float* wq      = (const float*)d_in[12];
  const float* wk      = (const float*)d_in[13];
  const float* wv      = (const float*)d_in[14];
  const float* wo      = (const float*)d_in[15];
  const float* wo_b    = (const float*)d_in[16];
  const float* ln2_g   = (const float*)d_in[17];
  const float* ln2_b   = (const float*)d_in[18];
  const float* ff_w1   = (const float*)d_in[19];
  const float* ff_b1   = (const float*)d_in[20];
  const float* ff_w2   = (const float*)d_in[21];
  const float* ff_b2   = (const float*)d_in[22];
  const float* norm_g  = (const float*)d_in[23];
  const float* norm_b  = (const float*)d_in[24];
  const float* out_w   = (const float*)d_in[25];
  const float* out_b   = (const float*)d_in[26];
  const float* alpha   = (const float*)d_in[27];

  char* ws = (char*)d_ws;
  bf16*  h      = (bf16*)(ws + 0);             // 16,777,216 (bf16 residual stream)
  float* te1    = (float*)(ws + 16777216);     // 65,536
  float* te2    = (float*)(ws + 16842752);     // 16,384
  float* psum   = (float*)(ws + 16859136);     // 131,072
  float* ctx    = (float*)(ws + 16990208);     // 524,288
  float* part   = (float*)(ws + 17514496);     // 8,388,608
  bf16* nbuf    = (bf16*)(ws + 25903104);      // 16,777,216
  bf16* qkvb    = (bf16*)(ws + 42680320);      // 50,331,648
  bf16* abuf    = (bf16*)(ws + 93011968);      // 16,777,216
  bf16* gbuf    = qkvb;                        // ff1 out spans qkv+abuf (both dead)
  bf16* xw      = (bf16*)(ws + 109789184);     // 4,194,304
  bf16* token_wT= (bf16*)(ws + 113983488);     // 131,072
  bf16* wqkvT   = (bf16*)(ws + 114114560);     // 6,291,456  [L][1536][512]
  bf16* woT     = (bf16*)(ws + 120406016);     // 2,097,152
  bf16* ff1T    = (bf16*)(ws + 122503168);     // 8,388,608
  bf16* ff2T    = (bf16*)(ws + 130891776);     // 8,388,608
  bf16* outwT   = (bf16*)(ws + 139280384);     // 131,072

  conv_kernel<<<2048, 256, 0, stream>>>(x_f, xw, 2097152);
  convT_kernel<<<dim3(4, 16, 1),  256, 0, stream>>>(token_w, token_wT, 128, 512, 65536, 65536);
  convT4_kernel<<<dim3(16, 16, 16), 256, 0, stream>>>(wq, wk, wv, wo, wqkvT, woT);
  convT_kernel<<<dim3(16, 64, 4), 256, 0, stream>>>(ff_w1, ff1T, 512, 2048, 1048576, 1048576);
  convT_kernel<<<dim3(64, 16, 4), 256, 0, stream>>>(ff_w2, ff2T, 2048, 512, 1048576, 1048576);
  convT_kernel<<<dim3(16, 4, 1),  256, 0, stream>>>(out_w, outwT, 512, 128, 65536, 65536);

  time1_kernel<<<256, 256, 0, stream>>>(t_i, time_w1, time_b1, te1);
  time2_kernel<<<64, 256, 0, stream>>>(te1, time_w2, time_b2, te2);

  // token embedding + pos/time add fused (gemm3 EPI5, K=128)
  gemm3_kernel<5, 128, 128><<<512, 512, 0, stream>>>(xw, token_wT, token_b, h, 512, 128, 4, ax1, ax2, te2);

  for (int l = 0; l < 4; l++) {
    ln_kernel<<<4096, 256, 0, stream>>>(h, ln1_g + l * 512, ln1_b + l * 512, nbuf);
    gemm3_kernel<0, 128, 256><<<768, 512, 0, stream>>>(nbuf, wqkvT + (size_t)l * 786432, nullptr, qkvb, 1536, 512, 6, nullptr, nullptr, nullptr);
    attn_kernel<<<dim3(16, 64), 256, 0, stream>>>(qkvb, abuf, part, psum);
    la2b_kernel<<<512, 256, 0, stream>>>(part, psum, ctx);
    la3_kernel<<<dim3(16, 32), 256, 0, stream>>>(qkvb, ctx, abuf);
    gemm3_kernel<2, 128, 128><<<512, 512, 0, stream>>>(abuf, woT + (size_t)l * 262144, wo_b + l * 512, h, 512, 512, 4, nullptr, nullptr, nullptr);
    ln_kernel<<<4096, 256, 0, stream>>>(h, ln2_g + l * 512, ln2_b + l * 512, nbuf);
    gemm3_kernel<3, 128, 256><<<1024, 512, 0, stream>>>(nbuf, ff1T + (size_t)l * 1048576, ff_b1 + l * 2048, gbuf, 2048, 512, 8, nullptr, nullptr, nullptr);
    gemm3_kernel<2, 128, 128><<<512, 512, 0, stream>>>(gbuf, ff2T + (size_t)l * 1048576, ff_b2 + l * 512, h, 512, 2048, 4, nullptr, nullptr, nullptr);
  }

  ln_kernel<<<4096, 256, 0, stream>>>(h, norm_g, norm_b, nbuf);
  gemm_kernel<<<128, 256, 0, stream>>>(nbuf, outwT, out_b, (float*)d_out, 128, 512, 1, alpha);
}

// Round 16
// 1001.957 us; speedup vs baseline: 1.0898x; 1.0898x over previous
//
#include <hip/hip_runtime.h>

typedef __bf16 bf16;
typedef float f32x4 __attribute__((ext_vector_type(4)));
typedef __bf16 b8v __attribute__((ext_vector_type(8)));
typedef __bf16 b4v __attribute__((ext_vector_type(4)));

#define S_LEN 2048
#define DMODEL 512
#define KDIM 128
#define NWIN 16
#define WIN 128
#define QKVS 1536   // fused qkv row stride

__device__ inline f32x4 mfma16(b8v a, b8v b, f32x4 c) {
  return __builtin_amdgcn_mfma_f32_16x16x32_bf16(a, b, c, 0, 0, 0);
}

__device__ inline void gload16(const bf16* g, bf16* l) {
  __builtin_amdgcn_global_load_lds(
      (const __attribute__((address_space(1))) void*)g,
      (__attribute__((address_space(3))) void*)l, 16, 0, 0);
}

template<int N>
__device__ inline void waitvm() { asm volatile("s_waitcnt vmcnt(%0)" :: "n"(N) : "memory"); }
template<int N>
__device__ inline void waitlgkm() { asm volatile("s_waitcnt lgkmcnt(%0)" :: "n"(N) : "memory"); }
__device__ inline void barrier_raw() { asm volatile("s_barrier" ::: "memory"); }

// ---------------- conversion kernels ----------------

__global__ __launch_bounds__(256) void conv_kernel(const float* __restrict__ in, bf16* __restrict__ out, int n) {
  int i4 = (blockIdx.x * 256 + threadIdx.x) * 4;
  if (i4 < n) {
    float4 v = *(const float4*)(in + i4);
    b4v o; o[0] = (bf16)v.x; o[1] = (bf16)v.y; o[2] = (bf16)v.z; o[3] = (bf16)v.w;
    *(b4v*)(out + i4) = o;
  }
}

// generic W (Kd x N) f32 -> WT (N x Kd) bf16
__global__ __launch_bounds__(256) void convT_kernel(const float* __restrict__ W, bf16* __restrict__ WT,
                                                    int Kd, int N, size_t in_ls, size_t out_ls) {
  __shared__ float tile[32][33];
  int k0 = blockIdx.x * 32, n0 = blockIdx.y * 32;
  const float* Wl = W + (size_t)blockIdx.z * in_ls;
  bf16* WTl = WT + (size_t)blockIdx.z * out_ls;
  int tx = threadIdx.x & 31, ty = threadIdx.x >> 5;
  #pragma unroll
  for (int i = 0; i < 4; i++)
    tile[ty + i*8][tx] = Wl[(size_t)(k0 + ty + i*8) * N + n0 + tx];
  __syncthreads();
  #pragma unroll
  for (int i = 0; i < 4; i++)
    WTl[(size_t)(n0 + ty + i*8) * Kd + k0 + tx] = (bf16)tile[tx][ty + i*8];
}

// fused transpose for wq/wk/wv/wo (all [4][512][512]); z = layer*4 + which
__global__ __launch_bounds__(256) void convT4_kernel(
    const float* __restrict__ wq, const float* __restrict__ wk,
    const float* __restrict__ wv, const float* __restrict__ wo,
    bf16* __restrict__ wqkvT, bf16* __restrict__ woT) {
  __shared__ float tile[32][33];
  int z = blockIdx.z, layer = z >> 2, which = z & 3;
  const float* W = (which == 0 ? wq : which == 1 ? wk : which == 2 ? wv : wo)
                   + (size_t)layer * 262144;
  bf16* WT = (which < 3) ? (wqkvT + (size_t)layer * 786432 + (size_t)which * 262144)
                         : (woT + (size_t)layer * 262144);
  int k0 = blockIdx.x * 32, n0 = blockIdx.y * 32;
  int tx = threadIdx.x & 31, ty = threadIdx.x >> 5;
  #pragma unroll
  for (int i = 0; i < 4; i++)
    tile[ty + i*8][tx] = W[(size_t)(k0 + ty + i*8) * 512 + n0 + tx];
  __syncthreads();
  #pragma unroll
  for (int i = 0; i < 4; i++)
    WT[(size_t)(n0 + ty + i*8) * 512 + k0 + tx] = (bf16)tile[tx][ty + i*8];
}

// ---------------- time embedding MLP ----------------

__global__ __launch_bounds__(256) void time1_kernel(const int* __restrict__ t,
    const float* __restrict__ w1, const float* __restrict__ b1, float* __restrict__ te1) {
  __shared__ float te[512];
  __shared__ float red[4][64];
  int b = blockIdx.x >> 5;
  int c0 = (blockIdx.x & 31) * 64;
  int tid = threadIdx.x;
  float tt = (float)t[b] * 4.0f;
  {
    float fr = expf((float)tid * (-9.210340371976184f / 255.0f));
    float e = tt * fr;
    te[tid] = sinf(e);
    te[tid + 256] = cosf(e);
  }
  __syncthreads();
  int lane = tid & 63, wv = tid >> 6;
  float acc = 0.f;
  const float* wcol = w1 + (size_t)(wv * 128) * 2048 + c0 + lane;
  for (int dd = 0; dd < 128; dd++) acc = fmaf(te[wv * 128 + dd], wcol[(size_t)dd * 2048], acc);
  red[wv][lane] = acc;
  __syncthreads();
  if (tid < 64) {
    float a = red[0][tid] + red[1][tid] + red[2][tid] + red[3][tid] + b1[c0 + tid];
    float sp = (a > 20.f) ? a : log1pf(expf(a));
    te1[b * 2048 + c0 + tid] = a * tanhf(sp);
  }
}

__global__ __launch_bounds__(256) void time2_kernel(const float* __restrict__ te1,
    const float* __restrict__ w2, const float* __restrict__ b2, float* __restrict__ te2) {
  __shared__ float hb[2048];
  __shared__ float red[4][64];
  int b = blockIdx.x >> 3;
  int c0 = (blockIdx.x & 7) * 64;
  int tid = threadIdx.x;
  for (int i = tid; i < 2048; i += 256) hb[i] = te1[b * 2048 + i];
  __syncthreads();
  int lane = tid & 63, wv = tid >> 6;
  float acc = 0.f;
  const float* wcol = w2 + (size_t)(wv * 512) * 512 + c0 + lane;
  for (int dd = 0; dd < 512; dd++) acc = fmaf(hb[wv * 512 + dd], wcol[(size_t)dd * 512], acc);
  red[wv][lane] = acc;
  __syncthreads();
  if (tid < 64)
    te2[b * 512 + c0 + tid] = red[0][tid] + red[1][tid] + red[2][tid] + red[3][tid] + b2[c0 + tid];
}

// ---------------- layernorm: bf16 in -> bf16 out ----------------

__global__ __launch_bounds__(256) void ln_kernel(const bf16* __restrict__ hsrc,
    const float* __restrict__ gg, const float* __restrict__ bb, bf16* __restrict__ out) {
  int row = blockIdx.x * 4 + (threadIdx.x >> 6);
  int lane = threadIdx.x & 63;
  const bf16* hr = hsrc + (size_t)row * 512 + lane * 8;
  b8v hv = *(const b8v*)hr;
  float xv[8];
  #pragma unroll
  for (int j = 0; j < 8; j++) xv[j] = (float)hv[j];
  float s = 0.f;
  #pragma unroll
  for (int j = 0; j < 8; j++) s += xv[j];
  #pragma unroll
  for (int off = 1; off < 64; off <<= 1) s += __shfl_xor(s, off);
  float mu = s * (1.f / 512.f);
  float vs = 0.f;
  #pragma unroll
  for (int j = 0; j < 8; j++) { float dd = xv[j] - mu; vs += dd * dd; }
  #pragma unroll
  for (int off = 1; off < 64; off <<= 1) vs += __shfl_xor(vs, off);
  float rstd = 1.f / sqrtf(vs * (1.f / 512.f) + 1e-5f);
  int dbase = lane * 8;
  bf16* orow = out + (size_t)row * 512 + dbase;
  #pragma unroll
  for (int j = 0; j < 8; j++)
    orow[j] = (bf16)((xv[j] - mu) * rstd * gg[dbase + j] + bb[dbase + j]);
}

// ---------------- phased MFMA GEMM (multi-block/CU) ----
// C(MxN) = A(MxK,bf16) * BT(NxK,bf16)^T ; 512 threads, 8 waves (2M x 4N); BK=32.
// 3 LDS k-tile buffers, 2-tiles-ahead prefetch; ONE vmcnt(LPI) + ONE s_barrier per
// K-tile. BM=128,BN=256 -> 72KB -> 2 blocks/CU; BM=128,BN=128 -> 48KB -> 3/CU.
// Measured: BN=256 best for K=512 weights (QKV/FF1); BN=128 best for WO/FF2.
// Direct scalar-store epilogue (LDS round-trip measured slower: round 15).
// EPI 0: Cb = acc ; 2: Cb += acc+bias ; 3: Cb = gelu_tanh(acc+bias)
// EPI 5: Cb = acc+bias + ax1 + ax2 + te2 (token embed + pos)
template<int EPI, int BM, int BN>
__global__ __launch_bounds__(512, 2) void gemm3_kernel(
    const bf16* __restrict__ A, const bf16* __restrict__ BT,
    const float* __restrict__ bias, bf16* __restrict__ Cb,
    int N, int Kd, int nbx,
    const float* __restrict__ q1, const float* __restrict__ q2, const float* __restrict__ q3) {
  constexpr int LA = BM / 128;
  constexpr int LB = BN / 128;
  constexpr int LPI = LA + LB;
  constexpr int EA = BM * 32;
  constexpr int EB = BN * 32;
  constexpr int ER = EA + EB;
  constexpr int MF = BM / 32;
  constexpr int NF = BN / 64;
  __shared__ bf16 lds[ER * 3];
  int tid = threadIdx.x;
  int lane = tid & 63, wid = tid >> 6;
  int g = lane >> 4, lr = lane & 15;
  int wm = wid >> 2, wn = wid & 3;
  int p = blockIdx.x;
  int cpx = (int)gridDim.x >> 3;
  int vid = (p & 7) * cpx + (p >> 3);
  int m0 = (vid / nbx) * BM;
  int n0 = (vid % nbx) * BN;
  f32x4 acc[MF][NF] = {};
  int rl = tid >> 2;
  int csw = ((tid & 3) ^ ((rl >> 1) & 3)) * 8;
  const bf16* pa = A + (size_t)(m0 + rl) * Kd + csw;
  const bf16* pb = BT + (size_t)(n0 + rl) * Kd + csw;
  int NT = Kd >> 5;
  auto stage = [&](int t, int buf) {
    int k0 = t << 5;
    bf16* base = lds + buf * ER + (wid << 9);
    #pragma unroll
    for (int rr = 0; rr < LA; rr++)
      gload16(pa + (size_t)(rr * 128) * Kd + k0, base + rr * 4096);
    #pragma unroll
    for (int rr = 0; rr < LB; rr++)
      gload16(pb + (size_t)(rr * 128) * Kd + k0, base + EA + rr * 4096);
  };
  stage(0, 0);
  stage(1, 1);
  for (int kt = 0; kt < NT; ++kt) {
    if (kt + 1 < NT) waitvm<LPI>();
    else             waitvm<0>();
    barrier_raw();
    const bf16* ba = lds + (kt % 3) * ER;
    const bf16* bb = ba + EA;
    if (kt + 2 < NT) stage(kt + 2, (kt + 2) % 3);
    b8v af[MF], bfr[NF];
    #pragma unroll
    for (int i = 0; i < MF; i++) {
      int ra = wm * (BM / 2) + i * 16 + lr;
      af[i] = *(const b8v*)(ba + ra * 32 + ((g * 8) ^ (((ra >> 1) & 3) << 3)));
    }
    #pragma unroll
    for (int j0 = 0; j0 < 2 && j0 < NF; j0++) {
      int rb = wn * (BN / 4) + j0 * 16 + lr;
      bfr[j0] = *(const b8v*)(bb + rb * 32 + ((g * 8) ^ (((rb >> 1) & 3) << 3)));
    }
    waitlgkm<0>();
    __builtin_amdgcn_sched_barrier(0);
    __builtin_amdgcn_s_setprio(1);
    #pragma unroll
    for (int i = 0; i < MF; i++) acc[i][0] = mfma16(af[i], bfr[0], acc[i][0]);
    __builtin_amdgcn_s_setprio(0);
    #pragma unroll
    for (int j = 1; j < NF; j++) {
      if (j + 1 < NF) {
        int rb = wn * (BN / 4) + (j + 1) * 16 + lr;
        bfr[j + 1] = *(const b8v*)(bb + rb * 32 + ((g * 8) ^ (((rb >> 1) & 3) << 3)));
        waitlgkm<1>();
      } else {
        waitlgkm<0>();
      }
      __builtin_amdgcn_sched_barrier(0);
      __builtin_amdgcn_s_setprio(1);
      #pragma unroll
      for (int i = 0; i < MF; i++) acc[i][j] = mfma16(af[i], bfr[j], acc[i][j]);
      __builtin_amdgcn_s_setprio(0);
    }
  }
  #pragma unroll
  for (int i = 0; i < MF; i++) {
    #pragma unroll
    for (int j = 0; j < NF; j++) {
      int col = n0 + wn * (BN / 4) + j * 16 + lr;
      float bv = (EPI != 0) ? bias[col] : 0.0f;
      #pragma unroll
      for (int r = 0; r < 4; r++) {
        int row = m0 + wm * (BM / 2) + i * 16 + g * 4 + r;
        float v = acc[i][j][r] + bv;
        if (EPI == 0) {
          Cb[(size_t)row * N + col] = (bf16)v;
        } else if (EPI == 2) {
          size_t idx = (size_t)row * N + col;
          Cb[idx] = (bf16)((float)Cb[idx] + v);
        } else if (EPI == 3) {
          float u = 1.5957691216057308f * (v + 0.044715f * v * v * v);
          float ge = v / (1.0f + __expf(-u));
          Cb[(size_t)row * N + col] = (bf16)ge;
        } else if (EPI == 5) {
          int b_ = row >> 11, s_ = row & 2047;
          float pv = q1[(s_ >> 7) * 512 + col] + q2[(s_ & 127) * 512 + col] + q3[b_ * 512 + col];
          Cb[(size_t)row * N + col] = (bf16)(v + pv);
        }
      }
    }
  }
}

// ---------------- small-GEMM kernel (output EPI4 transpose) ----
__global__ __launch_bounds__(256) void gemm_kernel(
    const bf16* __restrict__ A, const bf16* __restrict__ BT,
    const float* __restrict__ bias, float* __restrict__ Cf,
    int N, int Kd, int nbx, const float* __restrict__ alphap) {
  __shared__ bf16 As[2][4096];
  __shared__ bf16 Bs[2][4096];
  int tid = threadIdx.x;
  int lane = tid & 63, wid = tid >> 6;
  int g = lane >> 4, lr = lane & 15;
  int wm = wid >> 1, wn = wid & 1;
  int p = blockIdx.x;
  int cpx = (int)gridDim.x >> 3;
  int vid = (p & 7) * cpx + (p >> 3);
  int m0 = (vid / nbx) * 128;
  int n0 = (vid % nbx) * 128;
  f32x4 acc[4][4] = {};
  int srow = wid * 16 + (lane >> 2);
  int scol = (lane & 3) * 8;
  const bf16* pa = A + (size_t)(m0 + srow) * Kd + scol;
  const bf16* pb = BT + (size_t)(n0 + srow) * Kd + scol;
  const size_t rstep = (size_t)64 * Kd;
  int nt = Kd >> 5;
  auto stage = [&](int buf, int k0) {
    bf16* lA = &As[buf][wid * 512];
    bf16* lB = &Bs[buf][wid * 512];
    gload16(pa + k0, lA);
    gload16(pa + rstep + k0, lA + 2048);
    gload16(pb + k0, lB);
    gload16(pb + rstep + k0, lB + 2048);
  };
  stage(0, 0);
  __syncthreads();
  int cur = 0;
  for (int t = 0; t < nt; ++t) {
    if (t + 1 < nt) stage(cur ^ 1, (t + 1) * 32);
    b8v af[4], bfv[4];
    #pragma unroll
    for (int i = 0; i < 4; i++) af[i]  = *(const b8v*)&As[cur][(wm * 64 + i * 16 + lr) * 32 + g * 8];
    #pragma unroll
    for (int i = 0; i < 4; i++) bfv[i] = *(const b8v*)&Bs[cur][(wn * 64 + i * 16 + lr) * 32 + g * 8];
    #pragma unroll
    for (int mf = 0; mf < 4; mf++)
      #pragma unroll
      for (int nf = 0; nf < 4; nf++)
        acc[mf][nf] = mfma16(af[mf], bfv[nf], acc[mf][nf]);
    __syncthreads();
    cur ^= 1;
  }
  __shared__ float Ts[32][130];
  float alp = alphap[0];
  int b_ = m0 >> 11, sb = m0 & 2047;
  #pragma unroll
  for (int cg = 0; cg < 4; cg++) {
    __syncthreads();
    if (wn == (cg >> 1)) {
      #pragma unroll
      for (int nfi = 0; nfi < 2; nfi++) {
        int nf = (cg & 1) * 2 + nfi;
        int cl = nfi * 16 + lr;
        float bv = bias[cg * 32 + cl];
        #pragma unroll
        for (int mf = 0; mf < 4; mf++)
          #pragma unroll
          for (int r = 0; r < 4; r++)
            Ts[cl][wm * 64 + mf * 16 + g * 4 + r] = alp * (acc[mf][nf][r] + bv);
      }
    }
    __syncthreads();
    int cl = tid >> 3, soff = (tid & 7) * 16;
    int col = cg * 32 + cl;
    float* dst = Cf + (size_t)b_ * (KDIM * S_LEN) + (size_t)col * S_LEN + sb + soff;
    #pragma unroll
    for (int q4 = 0; q4 < 4; q4++) {
      float4 v = {Ts[cl][soff + q4*4], Ts[cl][soff + q4*4 + 1], Ts[cl][soff + q4*4 + 2], Ts[cl][soff + q4*4 + 3]};
      *(float4*)(dst + q4 * 4) = v;
    }
  }
}

// ---------------- merged attention part 1: local attn (y<32) + la2 (y>=32) ----
__global__ __launch_bounds__(256) void attn_kernel(
    const bf16* __restrict__ qkv, bf16* __restrict__ ab,
    float* __restrict__ part, float* __restrict__ psum) {
  __shared__ __align__(16) char smem[70656];
  int tid = threadIdx.x;
  if (blockIdx.y < 32) {
    bf16 (*Ks)[72]  = (bf16(*)[72])(smem);
    bf16 (*Vt)[136] = (bf16(*)[136])(smem + 18432);
    bf16 (*Ps)[32][136] = (bf16(*)[32][136])(smem + 35840);
    int w = blockIdx.x;
    int b = blockIdx.y >> 2, hh = blockIdx.y & 3;
    int wid = tid >> 6, lane = tid & 63;
    int g = lane >> 4, lr = lane & 15;
    const size_t rowb = (size_t)b * S_LEN * QKVS;
    int qrow0 = w * WIN + wid * 32;
    b8v qf[2][2];
    #pragma unroll
    for (int mf = 0; mf < 2; mf++)
      #pragma unroll
      for (int kf = 0; kf < 2; kf++)
        qf[mf][kf] = *(const b8v*)(qkv + rowb + (size_t)(qrow0 + mf * 16 + lr) * QKVS + hh * 64 + kf * 32 + g * 8);
    float mrun[2][4], lrun[2][4];
    f32x4 oacc[2][4] = {};
    #pragma unroll
    for (int mf = 0; mf < 2; mf++)
      #pragma unroll
      for (int r = 0; r < 4; r++) { mrun[mf][r] = -3e38f; lrun[mf][r] = 0.f; }
    for (int c = 0; c < 3; c++) {
      int wc = w - 1 + c;
      if (wc < 0 || wc >= NWIN) continue;
      __syncthreads();
      {
        int row = tid >> 1, f0 = (tid & 1) * 32;
        const bf16* kp = qkv + rowb + (size_t)(wc * WIN + row) * QKVS + 512 + hh * 64 + f0;
        #pragma unroll
        for (int i = 0; i < 4; i++)
          *(b8v*)&Ks[row][f0 + i * 8] = *(const b8v*)(kp + i * 8);
        const bf16* vp = qkv + rowb + (size_t)(wc * WIN + row) * QKVS + 1024 + hh * 64 + f0;
        #pragma unroll
        for (int i = 0; i < 4; i++) {
          b8v vv = *(const b8v*)(vp + i * 8);
          #pragma unroll
          for (int j = 0; j < 8; j++) Vt[f0 + i * 8 + j][row] = vv[j];
        }
      }
      __syncthreads();
      f32x4 sc[2][8] = {};
      #pragma unroll
      for (int nf = 0; nf < 8; nf++) {
        #pragma unroll
        for (int kf = 0; kf < 2; kf++) {
          b8v kfr = *(const b8v*)&Ks[nf * 16 + lr][kf * 32 + g * 8];
          sc[0][nf] = mfma16(qf[0][kf], kfr, sc[0][nf]);
          sc[1][nf] = mfma16(qf[1][kf], kfr, sc[1][nf]);
        }
      }
      #pragma unroll
      for (int mf = 0; mf < 2; mf++) {
        #pragma unroll
        for (int r = 0; r < 4; r++) {
          float cm = -3e38f;
          #pragma unroll
          for (int nf = 0; nf < 8; nf++) { sc[mf][nf][r] *= 0.125f; cm = fmaxf(cm, sc[mf][nf][r]); }
          cm = fmaxf(cm, __shfl_xor(cm, 1));
          cm = fmaxf(cm, __shfl_xor(cm, 2));
          cm = fmaxf(cm, __shfl_xor(cm, 4));
          cm = fmaxf(cm, __shfl_xor(cm, 8));
          float mnew = fmaxf(mrun[mf][r], cm);
          float corr = __expf(mrun[mf][r] - mnew);
          float rs = 0.f;
          #pragma unroll
          for (int nf = 0; nf < 8; nf++) { float pv = __expf(sc[mf][nf][r] - mnew); sc[mf][nf][r] = pv; rs += pv; }
          rs += __shfl_xor(rs, 1); rs += __shfl_xor(rs, 2);
          rs += __shfl_xor(rs, 4); rs += __shfl_xor(rs, 8);
          lrun[mf][r] = lrun[mf][r] * corr + rs;
          mrun[mf][r] = mnew;
          #pragma unroll
          for (int vf = 0; vf < 4; vf++) oacc[mf][vf][r] *= corr;
        }
      }
      #pragma unroll
      for (int mf = 0; mf < 2; mf++)
        #pragma unroll
        for (int nf = 0; nf < 8; nf++)
          #pragma unroll
          for (int r = 0; r < 4; r++)
            Ps[wid][mf * 16 + g * 4 + r][nf * 16 + lr] = (bf16)sc[mf][nf][r];
      #pragma unroll
      for (int kf2 = 0; kf2 < 4; kf2++) {
        b8v pa0 = *(const b8v*)&Ps[wid][lr][kf2 * 32 + g * 8];
        b8v pa1 = *(const b8v*)&Ps[wid][16 + lr][kf2 * 32 + g * 8];
        #pragma unroll
        for (int vf = 0; vf < 4; vf++) {
          b8v vv = *(const b8v*)&Vt[vf * 16 + lr][kf2 * 32 + g * 8];
          oacc[0][vf] = mfma16(pa0, vv, oacc[0][vf]);
          oacc[1][vf] = mfma16(pa1, vv, oacc[1][vf]);
        }
      }
    }
    #pragma unroll
    for (int mf = 0; mf < 2; mf++) {
      #pragma unroll
      for (int r = 0; r < 4; r++) {
        float inv = 1.0f / lrun[mf][r];
        int row = qrow0 + mf * 16 + g * 4 + r;
        #pragma unroll
        for (int vf = 0; vf < 4; vf++)
          ab[(size_t)b * S_LEN * DMODEL + (size_t)row * DMODEL + hh * 64 + vf * 16 + lr] = (bf16)(oacc[mf][vf][r] * inv);
      }
    }
  } else {
    float (*ke)[65]  = (float(*)[65])(smem);
    float (*vsh)[65] = (float(*)[65])(smem + 33280);
    float (*red)[64] = (float(*)[64])(smem + 66560);
    int ch = blockIdx.x, bh = blockIdx.y - 32;
    int b = bh >> 2, hh = bh & 3;
    const float scale = 0.35355339059327373f;
    const size_t base = ((size_t)b * S_LEN + (size_t)ch * 128) * QKVS;
    const bf16* kp = qkv + base + 768 + hh * 64;
    const bf16* vp = qkv + base + 1280 + hh * 64;
    for (int i = tid; i < 1024; i += 256) {
      int s = i >> 3, d0 = (i & 7) * 8;
      b8v kv = *(const b8v*)(kp + (size_t)s * QKVS + d0);
      b8v vv = *(const b8v*)(vp + (size_t)s * QKVS + d0);
      #pragma unroll
      for (int j = 0; j < 8; j++) {
        ke[s][d0 + j] = __expf((float)kv[j] * scale);
        vsh[s][d0 + j] = (float)vv[j];
      }
    }
    __syncthreads();
    int d = tid & 63, sg = tid >> 6;
    float ps = 0.f;
    for (int s = sg * 32; s < sg * 32 + 32; s++) ps += ke[s][d];
    red[sg][d] = ps;
    int e = tid & 63, dg = tid >> 6;
    float accv[16] = {};
    for (int s = 0; s < 128; s++) {
      float vv2 = vsh[s][e];
      #pragma unroll
      for (int i = 0; i < 16; i++) accv[i] = fmaf(ke[s][dg * 16 + i], vv2, accv[i]);
    }
    __syncthreads();
    float* pp = part + ((size_t)ch * 32 + bh) * 4096 + (size_t)dg * 16 * 64 + e;
    #pragma unroll
    for (int i = 0; i < 16; i++) pp[i * 64] = accv[i];
    if (tid < 64)
      psum[((size_t)ch * 32 + bh) * 64 + tid] = red[0][tid] + red[1][tid] + red[2][tid] + red[3][tid];
  }
}

__global__ __launch_bounds__(256) void la2b_kernel(const float* __restrict__ part,
    const float* __restrict__ psum, float* __restrict__ ctx) {
  int idx = blockIdx.x * 256 + threadIdx.x;    // 131072 total
  int bh = idx >> 12;
  int d = (idx >> 6) & 63;
  float s = 0.f, cs = 0.f;
  for (int c = 0; c < 16; c++) {
    s += part[(size_t)c * 131072 + idx];
    cs += psum[(size_t)(c * 32 + bh) * 64 + d];
  }
  ctx[idx] = s / cs;
}

__global__ __launch_bounds__(256) void la3_kernel(const bf16* __restrict__ qkv,
    const float* __restrict__ ctx, bf16* __restrict__ ab) {
  int ch = blockIdx.x, bh = blockIdx.y;
  int b = bh >> 2, hh = bh & 3;
  __shared__ float cs[64][65];
  int tid = threadIdx.x;
  for (int i = tid; i < 4096; i += 256) cs[i >> 6][i & 63] = ctx[(size_t)bh * 4096 + i];
  __syncthreads();
  int s = ch * 128 + (tid >> 1);
  int e0 = (tid & 1) * 32;
  const float scale = 0.35355339059327373f;
  const bf16* qr = qkv + ((size_t)b * S_LEN + s) * QKVS + 256 + hh * 64;
  float qv[64];
  float mx = -3e38f;
  #pragma unroll
  for (int i = 0; i < 8; i++) {
    b8v qq = *(const b8v*)(qr + i * 8);
    #pragma unroll
    for (int j = 0; j < 8; j++) { qv[i * 8 + j] = (float)qq[j] * scale; mx = fmaxf(mx, qv[i * 8 + j]); }
  }
  float sum = 0.f;
  #pragma unroll
  for (int dd = 0; dd < 64; dd++) { qv[dd] = __expf(qv[dd] - mx); sum += qv[dd]; }
  float inv = 1.f / sum;
  float o[32] = {};
  #pragma unroll
  for (int dd = 0; dd < 64; dd++) {
    float qq = qv[dd] * inv;
    #pragma unroll
    for (int j = 0; j < 32; j++) o[j] = fmaf(qq, cs[dd][e0 + j], o[j]);
  }
  bf16* op = ab + ((size_t)b * S_LEN + s) * DMODEL + 256 + hh * 64 + e0;
  #pragma unroll
  for (int j = 0; j < 32; j++) op[j] = (bf16)o[j];
}

// ---------------- launcher ----------------

extern "C" void kernel_launch(void* const* d_in, const int* in_sizes, int n_in,
                              void* d_out, int out_size, void* d_ws, size_t ws_size,
                              hipStream_t stream) {
  (void)in_sizes; (void)n_in; (void)out_size; (void)ws_size;
  const float* x_f     = (const float*)d_in[0];
  const int*   t_i     = (const int*)  d_in[1];
  const float* token_w = (const float*)d_in[2];
  const float* token_b = (const float*)d_in[3];
  const float* ax1     = (const float*)d_in[4];
  const float* ax2     = (const float*)d_in[5];
  const float* time_w1 = (const float*)d_in[6];
  const float* time_b1 = (const float*)d_in[7];
  const float* time_w2 = (const float*)d_in[8];
  const float* time_b2 = (const float*)d_in[9];
  const float* ln1_g   = (const float*)d_in[10];
  const float* ln1_b   = (const float*)d_in[11];
  const float* wq      = (const float*)d_in[12];
  const float* wk      = (const float*)d_in[13];
  const float* wv      = (const float*)d_in[14];
  const float* wo      = (const float*)d_in[15];
  const float* wo_b    = (const float*)d_in[16];
  const float* ln2_g   = (const float*)d_in[17];
  const float* ln2_b   = (const float*)d_in[18];
  const float* ff_w1   = (const float*)d_in[19];
  const float* ff_b1   = (const float*)d_in[20];
  const float* ff_w2   = (const float*)d_in[21];
  const float* ff_b2   = (const float*)d_in[22];
  const float* norm_g  = (const float*)d_in[23];
  const float* norm_b  = (const float*)d_in[24];
  const float* out_w   = (const float*)d_in[25];
  const float* out_b   = (const float*)d_in[26];
  const float* alpha   = (const float*)d_in[27];

  char* ws = (char*)d_ws;
  bf16*  h      = (bf16*)(ws + 0);             // 16,777,216 (bf16 residual stream)
  float* te1    = (float*)(ws + 16777216);     // 65,536
  float* te2    = (float*)(ws + 16842752);     // 16,384
  float* psum   = (float*)(ws + 16859136);     // 131,072
  float* ctx    = (float*)(ws + 16990208);     // 524,288
  float* part   = (float*)(ws + 17514496);     // 8,388,608
  bf16* nbuf    = (bf16*)(ws + 25903104);      // 16,777,216
  bf16* qkvb    = (bf16*)(ws + 42680320);      // 50,331,648
  bf16* abuf    = (bf16*)(ws + 93011968);      // 16,777,216
  bf16* gbuf    = qkvb;                        // ff1 out spans qkv+abuf (both dead)
  bf16* xw      = (bf16*)(ws + 109789184);     // 4,194,304
  bf16* token_wT= (bf16*)(ws + 113983488);     // 131,072
  bf16* wqkvT   = (bf16*)(ws + 114114560);     // 6,291,456  [L][1536][512]
  bf16* woT     = (bf16*)(ws + 120406016);     // 2,097,152
  bf16* ff1T    = (bf16*)(ws + 122503168);     // 8,388,608
  bf16* ff2T    = (bf16*)(ws + 130891776);     // 8,388,608
  bf16* outwT   = (bf16*)(ws + 139280384);     // 131,072

  conv_kernel<<<2048, 256, 0, stream>>>(x_f, xw, 2097152);
  convT_kernel<<<dim3(4, 16, 1),  256, 0, stream>>>(token_w, token_wT, 128, 512, 65536, 65536);
  convT4_kernel<<<dim3(16, 16, 16), 256, 0, stream>>>(wq, wk, wv, wo, wqkvT, woT);
  convT_kernel<<<dim3(16, 64, 4), 256, 0, stream>>>(ff_w1, ff1T, 512, 2048, 1048576, 1048576);
  convT_kernel<<<dim3(64, 16, 4), 256, 0, stream>>>(ff_w2, ff2T, 2048, 512, 1048576, 1048576);
  convT_kernel<<<dim3(16, 4, 1),  256, 0, stream>>>(out_w, outwT, 512, 128, 65536, 65536);

  time1_kernel<<<256, 256, 0, stream>>>(t_i, time_w1, time_b1, te1);
  time2_kernel<<<64, 256, 0, stream>>>(te1, time_w2, time_b2, te2);

  // token embedding + pos/time add fused (gemm3 EPI5, K=128)
  gemm3_kernel<5, 128, 128><<<512, 512, 0, stream>>>(xw, token_wT, token_b, h, 512, 128, 4, ax1, ax2, te2);

  for (int l = 0; l < 4; l++) {
    ln_kernel<<<4096, 256, 0, stream>>>(h, ln1_g + l * 512, ln1_b + l * 512, nbuf);
    gemm3_kernel<0, 128, 256><<<768, 512, 0, stream>>>(nbuf, wqkvT + (size_t)l * 786432, nullptr, qkvb, 1536, 512, 6, nullptr, nullptr, nullptr);
    attn_kernel<<<dim3(16, 64), 256, 0, stream>>>(qkvb, abuf, part, psum);
    la2b_kernel<<<512, 256, 0, stream>>>(part, psum, ctx);
    la3_kernel<<<dim3(16, 32), 256, 0, stream>>>(qkvb, ctx, abuf);
    gemm3_kernel<2, 128, 128><<<512, 512, 0, stream>>>(abuf, woT + (size_t)l * 262144, wo_b + l * 512, h, 512, 512, 4, nullptr, nullptr, nullptr);
    ln_kernel<<<4096, 256, 0, stream>>>(h, ln2_g + l * 512, ln2_b + l * 512, nbuf);
    gemm3_kernel<3, 128, 256><<<1024, 512, 0, stream>>>(nbuf, ff1T + (size_t)l * 1048576, ff_b1 + l * 2048, gbuf, 2048, 512, 8, nullptr, nullptr, nullptr);
    gemm3_kernel<2, 128, 128><<<512, 512, 0, stream>>>(gbuf, ff2T + (size_t)l * 1048576, ff_b2 + l * 512, h, 512, 2048, 4, nullptr, nullptr, nullptr);
  }

  ln_kernel<<<4096, 256, 0, stream>>>(h, norm_g, norm_b, nbuf);
  gemm_kernel<<<128, 256, 0, stream>>>(nbuf, outwT, out_b, (float*)d_out, 128, 512, 1, alpha);
}